// Round 1
// baseline (1503.565 us; speedup 1.0000x reference)
//
#include <hip/hip_runtime.h>

#define NN 100000

// ---------------------------------------------------------------------------
// Edge scatter: agg[dst] += x[src], deg[dst] += 1  (mean aggregation numerator)
// 8 threads per edge, each handling a float4 (32 floats / edge).
// Consecutive 8 lanes read consecutive 16B of the same source row -> the
// 128B row gather is coalesced within the lane-group.
// ---------------------------------------------------------------------------
__global__ void scatter_kernel(const float* __restrict__ x,
                               const int* __restrict__ src,
                               const int* __restrict__ dst,
                               float* __restrict__ agg,
                               float* __restrict__ deg,   // may be nullptr
                               int E) {
    int tid = blockIdx.x * blockDim.x + threadIdx.x;
    int e = tid >> 3;
    int c = tid & 7;
    if (e >= E) return;
    int s = src[e];
    int d = dst[e];
    const float4 v = *reinterpret_cast<const float4*>(x + (size_t)s * 32 + c * 4);
    float* a = agg + (size_t)d * 32 + c * 4;
    unsafeAtomicAdd(a + 0, v.x);
    unsafeAtomicAdd(a + 1, v.y);
    unsafeAtomicAdd(a + 2, v.z);
    unsafeAtomicAdd(a + 3, v.w);
    if (deg != nullptr && c == 0) unsafeAtomicAdd(deg + d, 1.0f);
}

// ---------------------------------------------------------------------------
// Layer-1 dense epilogue: h = relu( (agg/deg) @ W_l + x @ W_r + b )
// 256 threads = 8 nodes x 32 output features. Weights staged in LDS.
// ---------------------------------------------------------------------------
__global__ void dense1_kernel(const float* __restrict__ x,
                              const float* __restrict__ agg,
                              const float* __restrict__ deg,
                              const float* __restrict__ Wl,
                              const float* __restrict__ Wr,
                              const float* __restrict__ b,
                              float* __restrict__ h) {
    __shared__ float sWl[32 * 32];
    __shared__ float sWr[32 * 32];
    __shared__ float sb[32];
    int t = threadIdx.x;
    for (int i = t; i < 1024; i += 256) { sWl[i] = Wl[i]; sWr[i] = Wr[i]; }
    if (t < 32) sb[t] = b[t];
    __syncthreads();

    int node = blockIdx.x * 8 + (t >> 5);
    if (node >= NN) return;
    int o = t & 31;

    float rd = 1.0f / fmaxf(deg[node], 1.0f);
    float acc = sb[o];
    const float* ar = agg + (size_t)node * 32;
    const float* xr = x + (size_t)node * 32;
#pragma unroll
    for (int k = 0; k < 32; ++k) {
        acc += ar[k] * rd * sWl[k * 32 + o] + xr[k] * sWr[k * 32 + o];
    }
    h[(size_t)node * 32 + o] = fmaxf(acc, 0.0f);
}

// ---------------------------------------------------------------------------
// Layer-2 dense epilogue: out = (agg/deg) @ W2_l + h @ W2_r + b2   (no relu)
// 256 threads = 16 nodes x 16 output features.
// ---------------------------------------------------------------------------
__global__ void dense2_kernel(const float* __restrict__ h,
                              const float* __restrict__ agg,
                              const float* __restrict__ deg,
                              const float* __restrict__ Wl,
                              const float* __restrict__ Wr,
                              const float* __restrict__ b,
                              float* __restrict__ out) {
    __shared__ float sWl[32 * 16];
    __shared__ float sWr[32 * 16];
    __shared__ float sb[16];
    int t = threadIdx.x;
    for (int i = t; i < 512; i += 256) { sWl[i] = Wl[i]; sWr[i] = Wr[i]; }
    if (t < 16) sb[t] = b[t];
    __syncthreads();

    int node = blockIdx.x * 16 + (t >> 4);
    if (node >= NN) return;
    int o = t & 15;

    float rd = 1.0f / fmaxf(deg[node], 1.0f);
    float acc = sb[o];
    const float* ar = agg + (size_t)node * 32;
    const float* hr = h + (size_t)node * 32;
#pragma unroll
    for (int k = 0; k < 32; ++k) {
        acc += ar[k] * rd * sWl[k * 16 + o] + hr[k] * sWr[k * 16 + o];
    }
    out[(size_t)node * 16 + o] = acc;
}

extern "C" void kernel_launch(void* const* d_in, const int* in_sizes, int n_in,
                              void* d_out, int out_size, void* d_ws, size_t ws_size,
                              hipStream_t stream) {
    const float* x   = (const float*)d_in[0];
    const int*   ei  = (const int*)d_in[1];
    const float* W1l = (const float*)d_in[2];
    const float* W1r = (const float*)d_in[3];
    const float* b1  = (const float*)d_in[4];
    const float* W2l = (const float*)d_in[5];
    const float* W2r = (const float*)d_in[6];
    const float* b2  = (const float*)d_in[7];
    float* out = (float*)d_out;

    const int E = in_sizes[1] / 2;
    const int* src = ei;
    const int* dst = ei + E;

    // Workspace layout: agg[N*32] | deg[N] | h[N*32]
    float* agg = (float*)d_ws;
    float* deg = agg + (size_t)NN * 32;
    float* h   = deg + NN;

    // Zero agg + deg (ws is poisoned 0xAA before every timed launch).
    hipMemsetAsync(agg, 0, ((size_t)NN * 32 + NN) * sizeof(float), stream);

    // Layer 1
    int sc_blocks = (E * 8 + 255) / 256;
    scatter_kernel<<<sc_blocks, 256, 0, stream>>>(x, src, dst, agg, deg, E);
    dense1_kernel<<<(NN + 7) / 8, 256, 0, stream>>>(x, agg, deg, W1l, W1r, b1, h);

    // Layer 2 (reuse agg)
    hipMemsetAsync(agg, 0, (size_t)NN * 32 * sizeof(float), stream);
    scatter_kernel<<<sc_blocks, 256, 0, stream>>>(h, src, dst, agg, nullptr, E);
    dense2_kernel<<<(NN + 15) / 16, 256, 0, stream>>>(h, agg, deg, W2l, W2r, b2, out);
}

// Round 4
// 396.298 us; speedup vs baseline: 3.7940x; 3.7940x over previous
//
#include <hip/hip_runtime.h>

#define NN 100000
#define SCAN_TILE 256
#define NTILES ((NN + SCAN_TILE - 1) / SCAN_TILE)   // 391

// ---------------------------------------------------------------------------
// 1) Degree histogram: cnt[dst]++ per edge (int atomics, 32x fewer than before)
// ---------------------------------------------------------------------------
__global__ void hist_kernel(const int* __restrict__ dst, int* __restrict__ cnt, int E) {
    int e = blockIdx.x * blockDim.x + threadIdx.x;
    if (e < E) atomicAdd(&cnt[dst[e]], 1);
}

// ---------------------------------------------------------------------------
// 2a) Per-tile exclusive scan (in place), tile sums out.
// ---------------------------------------------------------------------------
__global__ void scan_tiles_kernel(int* __restrict__ data, int* __restrict__ bsums, int n) {
    __shared__ int s[SCAN_TILE];
    int t = threadIdx.x;
    int i = blockIdx.x * SCAN_TILE + t;
    int v = (i < n) ? data[i] : 0;
    s[t] = v;
    __syncthreads();
    for (int off = 1; off < SCAN_TILE; off <<= 1) {   // Hillis-Steele inclusive
        int add = (t >= off) ? s[t - off] : 0;
        __syncthreads();
        s[t] += add;
        __syncthreads();
    }
    if (i < n) data[i] = s[t] - v;                    // exclusive
    if (t == SCAN_TILE - 1) bsums[blockIdx.x] = s[t];
}

// ---------------------------------------------------------------------------
// 2b) Scan the 391 tile sums (one block).
// ---------------------------------------------------------------------------
__global__ void scan_bsums_kernel(int* __restrict__ bsums, int nb) {
    __shared__ int s[512];
    int t = threadIdx.x;
    int v = (t < nb) ? bsums[t] : 0;
    s[t] = v;
    __syncthreads();
    for (int off = 1; off < 512; off <<= 1) {
        int add = (t >= off) ? s[t - off] : 0;
        __syncthreads();
        s[t] += add;
        __syncthreads();
    }
    if (t < nb) bsums[t] = s[t] - v;                  // exclusive tile offsets
}

// ---------------------------------------------------------------------------
// 2c) Add tile offsets back.
// ---------------------------------------------------------------------------
__global__ void scan_add_kernel(int* __restrict__ data, const int* __restrict__ bsums, int n) {
    int i = blockIdx.x * blockDim.x + threadIdx.x;
    if (i < n) data[i] += bsums[blockIdx.x];
}

// ---------------------------------------------------------------------------
// 3) CSR fill. cursor == scanned rowptr; after this kernel rowptr[d] holds the
//    INCLUSIVE prefix (= row end), so row d = [rowptr[d-1], rowptr[d]).
// ---------------------------------------------------------------------------
__global__ void fill_kernel(const int* __restrict__ src, const int* __restrict__ dst,
                            int* __restrict__ cursor, int* __restrict__ csr, int E) {
    int e = blockIdx.x * blockDim.x + threadIdx.x;
    if (e < E) {
        int pos = atomicAdd(&cursor[dst[e]], 1);
        csr[pos] = src[e];
    }
}

// ---------------------------------------------------------------------------
// 4) Gather-mean: 8 lanes per node, float4 per lane. No atomics.
//    mean[d] = sum_{j in row d} x[csr[j]] / max(deg,1)
// ---------------------------------------------------------------------------
__global__ void agg_kernel(const float* __restrict__ x, const int* __restrict__ rowend,
                           const int* __restrict__ csr, float* __restrict__ mean) {
    int tid = blockIdx.x * blockDim.x + threadIdx.x;
    int d = tid >> 3;
    int c = tid & 7;
    if (d >= NN) return;
    int start = (d == 0) ? 0 : rowend[d - 1];
    int end = rowend[d];
    float4 acc = {0.f, 0.f, 0.f, 0.f};
    for (int j = start; j < end; ++j) {
        int s = csr[j];
        const float4 v = *reinterpret_cast<const float4*>(x + (size_t)s * 32 + c * 4);
        acc.x += v.x; acc.y += v.y; acc.z += v.z; acc.w += v.w;
    }
    float rd = 1.0f / fmaxf((float)(end - start), 1.0f);
    float4 m = {acc.x * rd, acc.y * rd, acc.z * rd, acc.w * rd};
    *reinterpret_cast<float4*>(mean + (size_t)d * 32 + c * 4) = m;
}

// ---------------------------------------------------------------------------
// Dense epilogues (weights in LDS). mean is pre-divided.
// ---------------------------------------------------------------------------
__global__ void dense1_kernel(const float* __restrict__ x,
                              const float* __restrict__ mean,
                              const float* __restrict__ Wl,
                              const float* __restrict__ Wr,
                              const float* __restrict__ b,
                              float* __restrict__ h) {
    __shared__ float sWl[32 * 32];
    __shared__ float sWr[32 * 32];
    __shared__ float sb[32];
    int t = threadIdx.x;
    for (int i = t; i < 1024; i += 256) { sWl[i] = Wl[i]; sWr[i] = Wr[i]; }
    if (t < 32) sb[t] = b[t];
    __syncthreads();

    int node = blockIdx.x * 8 + (t >> 5);
    if (node >= NN) return;
    int o = t & 31;
    float acc = sb[o];
    const float* mr = mean + (size_t)node * 32;
    const float* xr = x + (size_t)node * 32;
#pragma unroll
    for (int k = 0; k < 32; ++k)
        acc += mr[k] * sWl[k * 32 + o] + xr[k] * sWr[k * 32 + o];
    h[(size_t)node * 32 + o] = fmaxf(acc, 0.0f);
}

__global__ void dense2_kernel(const float* __restrict__ h,
                              const float* __restrict__ mean,
                              const float* __restrict__ Wl,
                              const float* __restrict__ Wr,
                              const float* __restrict__ b,
                              float* __restrict__ out) {
    __shared__ float sWl[32 * 16];
    __shared__ float sWr[32 * 16];
    __shared__ float sb[16];
    int t = threadIdx.x;
    for (int i = t; i < 512; i += 256) { sWl[i] = Wl[i]; sWr[i] = Wr[i]; }
    if (t < 16) sb[t] = b[t];
    __syncthreads();

    int node = blockIdx.x * 16 + (t >> 4);
    if (node >= NN) return;
    int o = t & 15;
    float acc = sb[o];
    const float* mr = mean + (size_t)node * 32;
    const float* hr = h + (size_t)node * 32;
#pragma unroll
    for (int k = 0; k < 32; ++k)
        acc += mr[k] * sWl[k * 16 + o] + hr[k] * sWr[k * 16 + o];
    out[(size_t)node * 16 + o] = acc;
}

extern "C" void kernel_launch(void* const* d_in, const int* in_sizes, int n_in,
                              void* d_out, int out_size, void* d_ws, size_t ws_size,
                              hipStream_t stream) {
    const float* x   = (const float*)d_in[0];
    const int*   ei  = (const int*)d_in[1];
    const float* W1l = (const float*)d_in[2];
    const float* W1r = (const float*)d_in[3];
    const float* b1  = (const float*)d_in[4];
    const float* W2l = (const float*)d_in[5];
    const float* W2r = (const float*)d_in[6];
    const float* b2  = (const float*)d_in[7];
    float* out = (float*)d_out;

    const int E = in_sizes[1] / 2;
    const int* src = ei;
    const int* dst = ei + E;

    // Workspace: rowptr[NN] | csr_src[E] | mean[NN*32] | h[NN*32] | bsums[512]
    char* ws = (char*)d_ws;
    int*   rowptr = (int*)ws;                                 ws += (size_t)NN * 4;
    int*   csr    = (int*)ws;                                 ws += (size_t)E * 4;
    float* mean   = (float*)ws;                               ws += (size_t)NN * 32 * 4;
    float* h      = (float*)ws;                               ws += (size_t)NN * 32 * 4;
    int*   bsums  = (int*)ws;

    // --- CSR build (once; reused by both layers) ---
    hipMemsetAsync(rowptr, 0, (size_t)NN * 4, stream);
    hist_kernel<<<(E + 255) / 256, 256, 0, stream>>>(dst, rowptr, E);
    scan_tiles_kernel<<<NTILES, SCAN_TILE, 0, stream>>>(rowptr, bsums, NN);
    scan_bsums_kernel<<<1, 512, 0, stream>>>(bsums, NTILES);
    scan_add_kernel<<<NTILES, SCAN_TILE, 0, stream>>>(rowptr, bsums, NN);
    fill_kernel<<<(E + 255) / 256, 256, 0, stream>>>(src, dst, rowptr, csr, E);
    // rowptr[d] is now the END of row d; start = rowptr[d-1] (0 for d=0).

    // --- Layer 1 ---
    agg_kernel<<<(NN * 8 + 255) / 256, 256, 0, stream>>>(x, rowptr, csr, mean);
    dense1_kernel<<<(NN + 7) / 8, 256, 0, stream>>>(x, mean, W1l, W1r, b1, h);

    // --- Layer 2 ---
    agg_kernel<<<(NN * 8 + 255) / 256, 256, 0, stream>>>(h, rowptr, csr, mean);
    dense2_kernel<<<(NN + 15) / 16, 256, 0, stream>>>(h, mean, W2l, W2r, b2, out);
}

// Round 5
// 380.131 us; speedup vs baseline: 3.9554x; 1.0425x over previous
//
#include <hip/hip_runtime.h>

#define NN 100000
#define SCAN_TILE 256
#define NTILES ((NN + SCAN_TILE - 1) / SCAN_TILE)   // 391

// ---------------------------------------------------------------------------
// CSR build: histogram -> scan -> cursor fill  (unchanged from R4)
// ---------------------------------------------------------------------------
__global__ void hist_kernel(const int* __restrict__ dst, int* __restrict__ cnt, int E) {
    int e = blockIdx.x * blockDim.x + threadIdx.x;
    if (e < E) atomicAdd(&cnt[dst[e]], 1);
}

__global__ void scan_tiles_kernel(int* __restrict__ data, int* __restrict__ bsums, int n) {
    __shared__ int s[SCAN_TILE];
    int t = threadIdx.x;
    int i = blockIdx.x * SCAN_TILE + t;
    int v = (i < n) ? data[i] : 0;
    s[t] = v;
    __syncthreads();
    for (int off = 1; off < SCAN_TILE; off <<= 1) {
        int add = (t >= off) ? s[t - off] : 0;
        __syncthreads();
        s[t] += add;
        __syncthreads();
    }
    if (i < n) data[i] = s[t] - v;                    // exclusive
    if (t == SCAN_TILE - 1) bsums[blockIdx.x] = s[t];
}

__global__ void scan_bsums_kernel(int* __restrict__ bsums, int nb) {
    __shared__ int s[512];
    int t = threadIdx.x;
    int v = (t < nb) ? bsums[t] : 0;
    s[t] = v;
    __syncthreads();
    for (int off = 1; off < 512; off <<= 1) {
        int add = (t >= off) ? s[t - off] : 0;
        __syncthreads();
        s[t] += add;
        __syncthreads();
    }
    if (t < nb) bsums[t] = s[t] - v;
}

__global__ void scan_add_kernel(int* __restrict__ data, const int* __restrict__ bsums, int n) {
    int i = blockIdx.x * blockDim.x + threadIdx.x;
    if (i < n) data[i] += bsums[blockIdx.x];
}

__global__ void fill_kernel(const int* __restrict__ src, const int* __restrict__ dst,
                            int* __restrict__ cursor, int* __restrict__ csr, int E) {
    int e = blockIdx.x * blockDim.x + threadIdx.x;
    if (e < E) {
        int pos = atomicAdd(&cursor[dst[e]], 1);
        csr[pos] = src[e];
    }
}

// ---------------------------------------------------------------------------
// Pre-transform layer 1:  y1 = x @ W1_l ,  z1 = x @ W1_r + b1   (N x 32 each)
// 256 thr = 8 nodes x 32 outs. mean(x)@W = mean(x@W) — aggregation is linear.
// ---------------------------------------------------------------------------
__global__ void transform1_kernel(const float* __restrict__ x,
                                  const float* __restrict__ Wl,
                                  const float* __restrict__ Wr,
                                  const float* __restrict__ b,
                                  float* __restrict__ y,
                                  float* __restrict__ z) {
    __shared__ float sWl[32 * 32];
    __shared__ float sWr[32 * 32];
    __shared__ float sb[32];
    int t = threadIdx.x;
    for (int i = t; i < 1024; i += 256) { sWl[i] = Wl[i]; sWr[i] = Wr[i]; }
    if (t < 32) sb[t] = b[t];
    __syncthreads();

    int node = blockIdx.x * 8 + (t >> 5);
    if (node >= NN) return;
    int o = t & 31;
    const float* xr = x + (size_t)node * 32;
    float accl = 0.0f, accr = sb[o];
#pragma unroll
    for (int k = 0; k < 32; ++k) {
        float xv = xr[k];
        accl += xv * sWl[k * 32 + o];
        accr += xv * sWr[k * 32 + o];
    }
    y[(size_t)node * 32 + o] = accl;
    z[(size_t)node * 32 + o] = accr;
}

// ---------------------------------------------------------------------------
// Pre-transform layer 2:  y2 = h @ W2_l ,  z2 = h @ W2_r + b2   (N x 16 each)
// 256 thr = 16 nodes x 16 outs.
// ---------------------------------------------------------------------------
__global__ void transform2_kernel(const float* __restrict__ h,
                                  const float* __restrict__ Wl,
                                  const float* __restrict__ Wr,
                                  const float* __restrict__ b,
                                  float* __restrict__ y,
                                  float* __restrict__ z) {
    __shared__ float sWl[32 * 16];
    __shared__ float sWr[32 * 16];
    __shared__ float sb[16];
    int t = threadIdx.x;
    for (int i = t; i < 512; i += 256) { sWl[i] = Wl[i]; sWr[i] = Wr[i]; }
    if (t < 16) sb[t] = b[t];
    __syncthreads();

    int node = blockIdx.x * 16 + (t >> 4);
    if (node >= NN) return;
    int o = t & 15;
    const float* hr = h + (size_t)node * 32;
    float accl = 0.0f, accr = sb[o];
#pragma unroll
    for (int k = 0; k < 32; ++k) {
        float hv = hr[k];
        accl += hv * sWl[k * 16 + o];
        accr += hv * sWr[k * 16 + o];
    }
    y[(size_t)node * 16 + o] = accl;
    z[(size_t)node * 16 + o] = accr;
}

// ---------------------------------------------------------------------------
// Fused gather-mean + epilogue, layer 1 (32-wide rows, 8 lanes/node):
//   h[d] = relu( mean_{s in row d} y1[s] + z1[d] )    -- h aliases z1 (in place)
// ---------------------------------------------------------------------------
__global__ void agg1_kernel(const float* __restrict__ y, const int* __restrict__ rowend,
                            const int* __restrict__ csr, float* __restrict__ hz) {
    int tid = blockIdx.x * blockDim.x + threadIdx.x;
    int d = tid >> 3;
    int c = tid & 7;
    if (d >= NN) return;
    int start = (d == 0) ? 0 : rowend[d - 1];
    int end = rowend[d];
    float4 acc = {0.f, 0.f, 0.f, 0.f};
    for (int j = start; j < end; ++j) {
        int s = csr[j];
        const float4 v = *reinterpret_cast<const float4*>(y + (size_t)s * 32 + c * 4);
        acc.x += v.x; acc.y += v.y; acc.z += v.z; acc.w += v.w;
    }
    float rd = 1.0f / fmaxf((float)(end - start), 1.0f);
    float4* hp = reinterpret_cast<float4*>(hz + (size_t)d * 32 + c * 4);
    float4 zv = *hp;
    float4 r;
    r.x = fmaxf(acc.x * rd + zv.x, 0.0f);
    r.y = fmaxf(acc.y * rd + zv.y, 0.0f);
    r.z = fmaxf(acc.z * rd + zv.z, 0.0f);
    r.w = fmaxf(acc.w * rd + zv.w, 0.0f);
    *hp = r;
}

// ---------------------------------------------------------------------------
// Fused gather-mean + epilogue, layer 2 (16-wide rows, 4 lanes/node):
//   out[d] = mean_{s in row d} y2[s] + z2[d]
// ---------------------------------------------------------------------------
__global__ void agg2_kernel(const float* __restrict__ y, const int* __restrict__ rowend,
                            const int* __restrict__ csr, const float* __restrict__ z,
                            float* __restrict__ out) {
    int tid = blockIdx.x * blockDim.x + threadIdx.x;
    int d = tid >> 2;
    int c = tid & 3;
    if (d >= NN) return;
    int start = (d == 0) ? 0 : rowend[d - 1];
    int end = rowend[d];
    float4 acc = {0.f, 0.f, 0.f, 0.f};
    for (int j = start; j < end; ++j) {
        int s = csr[j];
        const float4 v = *reinterpret_cast<const float4*>(y + (size_t)s * 16 + c * 4);
        acc.x += v.x; acc.y += v.y; acc.z += v.z; acc.w += v.w;
    }
    float rd = 1.0f / fmaxf((float)(end - start), 1.0f);
    const float4 zv = *reinterpret_cast<const float4*>(z + (size_t)d * 16 + c * 4);
    float4 r;
    r.x = acc.x * rd + zv.x;
    r.y = acc.y * rd + zv.y;
    r.z = acc.z * rd + zv.z;
    r.w = acc.w * rd + zv.w;
    *reinterpret_cast<float4*>(out + (size_t)d * 16 + c * 4) = r;
}

extern "C" void kernel_launch(void* const* d_in, const int* in_sizes, int n_in,
                              void* d_out, int out_size, void* d_ws, size_t ws_size,
                              hipStream_t stream) {
    const float* x   = (const float*)d_in[0];
    const int*   ei  = (const int*)d_in[1];
    const float* W1l = (const float*)d_in[2];
    const float* W1r = (const float*)d_in[3];
    const float* b1  = (const float*)d_in[4];
    const float* W2l = (const float*)d_in[5];
    const float* W2r = (const float*)d_in[6];
    const float* b2  = (const float*)d_in[7];
    float* out = (float*)d_out;

    const int E = in_sizes[1] / 2;
    const int* src = ei;
    const int* dst = ei + E;

    // Workspace: rowptr[NN] | csr[E] | A[NN*32] | B[NN*32] | bsums
    //   A: y1 (layer1), then reused as y2[NN*16] | z2[NN*16] (layer2)
    //   B: z1, overwritten in place by h
    char* ws = (char*)d_ws;
    int*   rowptr = (int*)ws;                     ws += (size_t)NN * 4;
    int*   csr    = (int*)ws;                     ws += (size_t)E * 4;
    float* A      = (float*)ws;                   ws += (size_t)NN * 32 * 4;
    float* B      = (float*)ws;                   ws += (size_t)NN * 32 * 4;
    int*   bsums  = (int*)ws;

    float* y1 = A;
    float* z1h = B;              // z1, becomes h in place
    float* y2 = A;               // first NN*16 of A
    float* z2 = A + (size_t)NN * 16;

    // --- CSR build (once; reused by both layers) ---
    hipMemsetAsync(rowptr, 0, (size_t)NN * 4, stream);
    hist_kernel<<<(E + 255) / 256, 256, 0, stream>>>(dst, rowptr, E);
    scan_tiles_kernel<<<NTILES, SCAN_TILE, 0, stream>>>(rowptr, bsums, NN);
    scan_bsums_kernel<<<1, 512, 0, stream>>>(bsums, NTILES);
    scan_add_kernel<<<NTILES, SCAN_TILE, 0, stream>>>(rowptr, bsums, NN);
    fill_kernel<<<(E + 255) / 256, 256, 0, stream>>>(src, dst, rowptr, csr, E);
    // rowptr[d] now = END of row d; start = rowptr[d-1] (0 for d=0).

    // --- Layer 1: transform then fused gather-mean+relu ---
    transform1_kernel<<<(NN + 7) / 8, 256, 0, stream>>>(x, W1l, W1r, b1, y1, z1h);
    agg1_kernel<<<(NN * 8 + 255) / 256, 256, 0, stream>>>(y1, rowptr, csr, z1h);

    // --- Layer 2: transform (reads h=B, writes into A) then fused gather ---
    transform2_kernel<<<(NN + 15) / 16, 256, 0, stream>>>(z1h, W2l, W2r, b2, y2, z2);
    agg2_kernel<<<(NN * 4 + 255) / 256, 256, 0, stream>>>(y2, rowptr, csr, z2, out);
}